// Round 2
// 815.859 us; speedup vs baseline: 1.4648x; 1.4648x over previous
//
#include <hip/hip_runtime.h>

#define LEAKY 0.2f
#define LN_EPS 1e-5f
#define SM_EPS 1e-16f
#define CAP 64   // max in-degree bucket; deg ~ Poisson(16), P(>64) ~ 1e-18
#define WPAD 68  // LDS row stride (floats): multiple of 4 keeps float4 aligned

// ---------------- K1: xl or xr = x @ W^T + b, W held in registers ----------------
// side = blockIdx.x & 1 selects {Wl->xl} or {Wr->xr}. Each block stages its
// 16 KB W through padded LDS once; lane i then owns row i of W in 16 float4
// VGPRs. Waves grid-stride over nodes: per node, 16 wave-uniform float4
// x-loads (all lanes same address -> L1 broadcast, 1 line/instr) + 64 FMAs
// + one coalesced 256B store. This removes v1's per-node 64-line W gather
// (32 instrs x 64 lines/wave ~ 2048 cy/wave -> 489 us at 4.9% VALUBusy).
// ~64+16 VGPR/lane -> no launch-bounds override, natural occupancy.
__global__ __launch_bounds__(256) void k_node_linear(
    const float* __restrict__ x,    // [N,64]
    const float* __restrict__ Wl,   // [64,64]
    const float* __restrict__ bl,   // [64]
    const float* __restrict__ Wr,   // [64,64]
    const float* __restrict__ br,   // [64]
    float* __restrict__ xl, float* __restrict__ xr,
    int* __restrict__ deg, int N)
{
    __shared__ __align__(16) float sW[64 * WPAD];

    const int tid = threadIdx.x;

    // zero deg for K2 (coalesced, grid-strided; 2048 blocks cover N)
    for (int i = blockIdx.x * 256 + tid; i < N; i += gridDim.x * 256) deg[i] = 0;

    const int side = blockIdx.x & 1;
    const float* __restrict__ W  = side ? Wr : Wl;
    const float* __restrict__ bv = side ? br : bl;
    float* __restrict__ dst      = side ? xr : xl;

    // coalesced global -> padded LDS (one-time per block)
    for (int i = tid; i < 4096; i += 256)
        sW[(i >> 6) * WPAD + (i & 63)] = W[i];
    __syncthreads();

    // lane i pulls row i of W into registers (16 x ds_read_b128, once/block)
    const int lane = tid & 63;
    float4 wq[16];
    #pragma unroll
    for (int q = 0; q < 16; ++q)
        wq[q] = *(const float4*)&sW[lane * WPAD + q * 4];
    const float bb = bv[lane];

    // one wave = one node-stream; (gridDim/2)*4 streams per side
    const int stream0 = (blockIdx.x >> 1) * 4 + (tid >> 6);
    const int nstream = (gridDim.x >> 1) * 4;
    for (int n = stream0; n < N; n += nstream) {
        const float4* xrow = (const float4*)(x + (long long)n * 64);
        float a = bb;
        #pragma unroll
        for (int q = 0; q < 16; ++q) {
            const float4 xv = xrow[q];
            const float4 w  = wq[q];
            a = fmaf(xv.x, w.x, fmaf(xv.y, w.y, fmaf(xv.z, w.z, fmaf(xv.w, w.w, a))));
        }
        dst[(long long)n * 64 + lane] = a;
    }
}

// ---------------- K2: bucket edges by destination (int atomics only) ----------------
__global__ __launch_bounds__(256) void k_bucket(
    const int* __restrict__ ei,   // [2,E]: row0=src, row1=dst
    int* __restrict__ deg,        // [N]
    int* __restrict__ slot,       // [N*CAP] edge ids grouped by dst
    int E)
{
    const int e = blockIdx.x * 256 + threadIdx.x;
    if (e >= E) return;
    const int dst = ei[E + e];
    const int pos = atomicAdd(deg + dst, 1);
    if (pos < CAP) slot[dst * CAP + pos] = e;
}

// ---------------- K3: per-dst gather + softmax + aggregate + epilogue ----------------
// One 64-lane wave per destination node (4 nodes / 256-thread block).
// lane = h*8+c. Per edge: recompute e_proj/logit in-register, 8-lane shfl
// reduce -> ex, accumulate ex*xl[src] (agg) and ex (denom) in registers.
// Epilogue fused: normalize, +bias, +x residual, LayerNorm, ReLU.
__global__ __launch_bounds__(256) void k_gather(
    const int* __restrict__ ei,
    const float* __restrict__ ea,    // [E,16]
    const float* __restrict__ We,    // [64,16]
    const float* __restrict__ att,   // [64]
    const float* __restrict__ xl, const float* __restrict__ xr,
    const int* __restrict__ deg, const int* __restrict__ slot,
    const float* __restrict__ x,
    const float* __restrict__ bias, const float* __restrict__ gamma,
    const float* __restrict__ beta,
    float* __restrict__ out, int N)
{
    const int lane = threadIdx.x & 63;
    const int n = blockIdx.x * 4 + (threadIdx.x >> 6);
    if (n >= N) return;

    // per-lane constants across all edges of this node
    const float4* w4 = (const float4*)(We + lane * 16);
    const float4 w0 = w4[0], w1 = w4[1], w2 = w4[2], w3 = w4[3];
    const float attv = att[lane];
    const float xrv = xr[(long long)n * 64 + lane];

    const int d = min(deg[n], CAP);
    const int* sl = slot + (long long)n * CAP;

    float acc = 0.f;   // aggregate for channel `lane`
    float ns  = 0.f;   // sum of ex for this head (replicated in 8 lanes)

    // software-pipelined gather loop: next {eid, src, xl, ea} prefetched
    // while computing the current edge.
    int eid = 0, src = 0;
    float xlv = 0.f;
    float4 e0, e1, e2, e3;
    if (d > 0) {
        eid = sl[0];
        src = ei[eid];
        xlv = xl[(long long)src * 64 + lane];
        const float4* eap = (const float4*)(ea + (long long)eid * 16);
        e0 = eap[0]; e1 = eap[1]; e2 = eap[2]; e3 = eap[3];
    }
    for (int i = 0; i < d; ++i) {
        const float xlc = xlv;
        const float4 c0 = e0, c1 = e1, c2 = e2, c3 = e3;
        if (i + 1 < d) {
            eid = sl[i + 1];
            src = ei[eid];
            xlv = xl[(long long)src * 64 + lane];
            const float4* eap = (const float4*)(ea + (long long)eid * 16);
            e0 = eap[0]; e1 = eap[1]; e2 = eap[2]; e3 = eap[3];
        }
        float ep = c0.x*w0.x + c0.y*w0.y + c0.z*w0.z + c0.w*w0.w
                 + c1.x*w1.x + c1.y*w1.y + c1.z*w1.z + c1.w*w1.w
                 + c2.x*w2.x + c2.y*w2.y + c2.z*w2.z + c2.w*w2.w
                 + c3.x*w3.x + c3.y*w3.y + c3.z*w3.z + c3.w*w3.w;
        float m = xlc + xrv + ep;
        m = (m > 0.f) ? m : LEAKY * m;           // leaky_relu
        float p = m * attv;
        p += __shfl_xor(p, 1, 64);               // reduce 8 lanes of this head
        p += __shfl_xor(p, 2, 64);
        p += __shfl_xor(p, 4, 64);
        const float ex = __expf(p);
        ns  += ex;
        acc = fmaf(ex, xlc, acc);
    }

    // fused epilogue
    const float a = acc / (ns + SM_EPS);
    const float hv = a + bias[lane] + x[(long long)n * 64 + lane];

    float s = hv;
    #pragma unroll
    for (int off = 32; off; off >>= 1) s += __shfl_xor(s, off, 64);
    const float mu = s * (1.f / 64.f);
    const float dd = hv - mu;
    float v = dd * dd;
    #pragma unroll
    for (int off = 32; off; off >>= 1) v += __shfl_xor(v, off, 64);
    const float var = v * (1.f / 64.f);

    float hn = dd * rsqrtf(var + LN_EPS) * gamma[lane] + beta[lane];
    out[(long long)n * 64 + lane] = (hn > 0.f) ? hn : 0.f;
}

extern "C" void kernel_launch(void* const* d_in, const int* in_sizes, int n_in,
                              void* d_out, int out_size, void* d_ws, size_t ws_size,
                              hipStream_t stream) {
    (void)n_in; (void)ws_size; (void)out_size;

    const float* x     = (const float*)d_in[0];
    const int*   ei    = (const int*)d_in[1];
    const float* ea    = (const float*)d_in[2];
    const float* Wl    = (const float*)d_in[3];
    const float* bl    = (const float*)d_in[4];
    const float* Wr    = (const float*)d_in[5];
    const float* br    = (const float*)d_in[6];
    const float* We    = (const float*)d_in[7];
    const float* att   = (const float*)d_in[8];
    const float* bias  = (const float*)d_in[9];
    const float* gamma = (const float*)d_in[10];
    const float* beta  = (const float*)d_in[11];

    const int N = in_sizes[0] / 64;   // x is [N,64]
    const int E = in_sizes[1] / 2;    // edge_index is [2,E]

    // ws: xl[N*64]f32 + xr[N*64]f32 + deg[N]i32 + slot[N*CAP]i32 = 77.2 MB
    float* w = (float*)d_ws;
    float* xl  = w;                   w += (size_t)N * 64;
    float* xr  = w;                   w += (size_t)N * 64;
    int* deg   = (int*)w;
    int* slot  = deg + N;

    float* out = (float*)d_out;

    // 2048 blocks: 1024/side, even split; also covers deg-zeroing of N
    k_node_linear<<<2048, 256, 0, stream>>>(
        x, Wl, bl, Wr, br, xl, xr, deg, N);

    k_bucket<<<(E + 255) / 256, 256, 0, stream>>>(ei, deg, slot, E);

    k_gather<<<(N + 3) / 4, 256, 0, stream>>>(
        ei, ea, We, att, xl, xr, deg, slot, x, bias, gamma, beta, out, N);
}

// Round 3
// 714.624 us; speedup vs baseline: 1.6723x; 1.1417x over previous
//
#include <hip/hip_runtime.h>

#define LEAKY 0.2f
#define LN_EPS 1e-5f
#define SM_EPS 1e-16f
#define CAP 64   // max in-degree bucket; deg ~ Poisson(16), P(>64) ~ 1e-18
#define WPAD 68  // LDS row stride (floats): multiple of 4 keeps float4 aligned

// ---------------- K1: xl or xr = x @ W^T + b, W held in registers ----------------
// side = blockIdx.x & 1 selects {Wl->xl} or {Wr->xr}. Each block stages its
// 16 KB W through padded LDS once; lane i then owns row i of W in 16 float4
// VGPRs. Waves grid-stride over nodes: per node, 16 wave-uniform float4
// x-loads (all lanes same address -> L1 broadcast, 1 line/instr) + 64 FMAs
// + one coalesced 256B store.
__global__ __launch_bounds__(256) void k_node_linear(
    const float* __restrict__ x,    // [N,64]
    const float* __restrict__ Wl,   // [64,64]
    const float* __restrict__ bl,   // [64]
    const float* __restrict__ Wr,   // [64,64]
    const float* __restrict__ br,   // [64]
    float* __restrict__ xl, float* __restrict__ xr,
    int* __restrict__ deg, int N)
{
    __shared__ __align__(16) float sW[64 * WPAD];

    const int tid = threadIdx.x;

    // zero deg for K2 (coalesced, grid-strided; 2048 blocks cover N)
    for (int i = blockIdx.x * 256 + tid; i < N; i += gridDim.x * 256) deg[i] = 0;

    const int side = blockIdx.x & 1;
    const float* __restrict__ W  = side ? Wr : Wl;
    const float* __restrict__ bv = side ? br : bl;
    float* __restrict__ dst      = side ? xr : xl;

    // coalesced global -> padded LDS (one-time per block)
    for (int i = tid; i < 4096; i += 256)
        sW[(i >> 6) * WPAD + (i & 63)] = W[i];
    __syncthreads();

    // lane i pulls row i of W into registers (16 x ds_read_b128, once/block)
    const int lane = tid & 63;
    float4 wq[16];
    #pragma unroll
    for (int q = 0; q < 16; ++q)
        wq[q] = *(const float4*)&sW[lane * WPAD + q * 4];
    const float bb = bv[lane];

    // one wave = one node-stream; (gridDim/2)*4 streams per side
    const int stream0 = (blockIdx.x >> 1) * 4 + (tid >> 6);
    const int nstream = (gridDim.x >> 1) * 4;
    for (int n = stream0; n < N; n += nstream) {
        const float4* xrow = (const float4*)(x + (long long)n * 64);
        float a = bb;
        #pragma unroll
        for (int q = 0; q < 16; ++q) {
            const float4 xv = xrow[q];
            const float4 w  = wq[q];
            a = fmaf(xv.x, w.x, fmaf(xv.y, w.y, fmaf(xv.z, w.z, fmaf(xv.w, w.w, a))));
        }
        dst[(long long)n * 64 + lane] = a;
    }
}

// ---------------- K2: bucket edges by destination (int atomics only) ----------------
__global__ __launch_bounds__(256) void k_bucket(
    const int* __restrict__ ei,   // [2,E]: row0=src, row1=dst
    int* __restrict__ deg,        // [N]
    int* __restrict__ slot,       // [N*CAP] edge ids grouped by dst
    int E)
{
    const int e = blockIdx.x * 256 + threadIdx.x;
    if (e >= E) return;
    const int dst = ei[E + e];
    const int pos = atomicAdd(deg + dst, 1);
    if (pos < CAP) slot[dst * CAP + pos] = e;
}

// ---------------- K3: per-dst gather + softmax + aggregate + epilogue ----------------
// One 64-lane wave per destination node (4 nodes / 256-thread block).
// lane = h*8+c. v3: the slot->ei->xl 3-deep dependent chain is collapsed by
// a wave-wide index hoist: lane i loads slot[i] (1 coalesced instr) and
// ei[eid_i] (1 gather instr, all 64 in flight at once). In the edge loop,
// src/eid come from __shfl (v_readlane, uniform i -> SGPR base), leaving a
// single-level xl/ea fetch pipelined 2-deep in explicit registers.
// Epilogue fused: normalize, +bias, +x residual, LayerNorm, ReLU.
__global__ __launch_bounds__(256) void k_gather(
    const int* __restrict__ ei,
    const float* __restrict__ ea,    // [E,16]
    const float* __restrict__ We,    // [64,16]
    const float* __restrict__ att,   // [64]
    const float* __restrict__ xl, const float* __restrict__ xr,
    const int* __restrict__ deg, const int* __restrict__ slot,
    const float* __restrict__ x,
    const float* __restrict__ bias, const float* __restrict__ gamma,
    const float* __restrict__ beta,
    float* __restrict__ out, int N)
{
    const int lane = threadIdx.x & 63;
    const int n = blockIdx.x * 4 + (threadIdx.x >> 6);
    if (n >= N) return;

    // per-lane constants across all edges of this node
    const float4* w4 = (const float4*)(We + lane * 16);
    const float4 w0 = w4[0], w1 = w4[1], w2 = w4[2], w3 = w4[3];
    const float attv = att[lane];
    const float xrv = xr[(long long)n * 64 + lane];

    const int d = min(deg[n], CAP);

    // wave-wide index hoist: all edge ids + src ids fetched in 2 instructions
    int veid = 0, vsrc = 0;
    if (lane < d) {
        veid = slot[(long long)n * CAP + lane];
        vsrc = ei[veid];
    }

    float acc = 0.f;   // aggregate for channel `lane`
    float ns  = 0.f;   // sum of ex for this head (replicated in 8 lanes)

    // depth-2 software pipeline over edges; explicit regs (no runtime-indexed
    // arrays -> no scratch). Stage A = edge i, stage B = edge i+1.
    float xlA = 0.f, xlB = 0.f;
    float4 a0, a1, a2, a3, b0, b1, b2, b3;
    a0 = a1 = a2 = a3 = b0 = b1 = b2 = b3 = make_float4(0.f, 0.f, 0.f, 0.f);

#define FETCH(j, XLV, E0, E1, E2, E3) do {                       \
        const int s_ = __shfl(vsrc, (j), 64);                    \
        const int e_ = __shfl(veid, (j), 64);                    \
        XLV = xl[(long long)s_ * 64 + lane];                     \
        const float4* p_ = (const float4*)(ea + (long long)e_ * 16); \
        E0 = p_[0]; E1 = p_[1]; E2 = p_[2]; E3 = p_[3];          \
    } while (0)

    if (d > 0) FETCH(0, xlA, a0, a1, a2, a3);
    if (d > 1) FETCH(1, xlB, b0, b1, b2, b3);

    for (int i = 0; i < d; ++i) {
        const float xlc = xlA;
        const float4 c0 = a0, c1 = a1, c2 = a2, c3 = a3;
        xlA = xlB; a0 = b0; a1 = b1; a2 = b2; a3 = b3;
        if (i + 2 < d) FETCH(i + 2, xlB, b0, b1, b2, b3);

        float ep = c0.x*w0.x + c0.y*w0.y + c0.z*w0.z + c0.w*w0.w
                 + c1.x*w1.x + c1.y*w1.y + c1.z*w1.z + c1.w*w1.w
                 + c2.x*w2.x + c2.y*w2.y + c2.z*w2.z + c2.w*w2.w
                 + c3.x*w3.x + c3.y*w3.y + c3.z*w3.z + c3.w*w3.w;
        float m = xlc + xrv + ep;
        m = (m > 0.f) ? m : LEAKY * m;           // leaky_relu
        float p = m * attv;
        p += __shfl_xor(p, 1, 64);               // reduce 8 lanes of this head
        p += __shfl_xor(p, 2, 64);
        p += __shfl_xor(p, 4, 64);
        const float ex = __expf(p);
        ns  += ex;
        acc = fmaf(ex, xlc, acc);
    }
#undef FETCH

    // fused epilogue
    const float a = acc / (ns + SM_EPS);
    const float hv = a + bias[lane] + x[(long long)n * 64 + lane];

    float s = hv;
    #pragma unroll
    for (int off = 32; off; off >>= 1) s += __shfl_xor(s, off, 64);
    const float mu = s * (1.f / 64.f);
    const float dd = hv - mu;
    float v = dd * dd;
    #pragma unroll
    for (int off = 32; off; off >>= 1) v += __shfl_xor(v, off, 64);
    const float var = v * (1.f / 64.f);

    float hn = dd * rsqrtf(var + LN_EPS) * gamma[lane] + beta[lane];
    out[(long long)n * 64 + lane] = (hn > 0.f) ? hn : 0.f;
}

extern "C" void kernel_launch(void* const* d_in, const int* in_sizes, int n_in,
                              void* d_out, int out_size, void* d_ws, size_t ws_size,
                              hipStream_t stream) {
    (void)n_in; (void)ws_size; (void)out_size;

    const float* x     = (const float*)d_in[0];
    const int*   ei    = (const int*)d_in[1];
    const float* ea    = (const float*)d_in[2];
    const float* Wl    = (const float*)d_in[3];
    const float* bl    = (const float*)d_in[4];
    const float* Wr    = (const float*)d_in[5];
    const float* br    = (const float*)d_in[6];
    const float* We    = (const float*)d_in[7];
    const float* att   = (const float*)d_in[8];
    const float* bias  = (const float*)d_in[9];
    const float* gamma = (const float*)d_in[10];
    const float* beta  = (const float*)d_in[11];

    const int N = in_sizes[0] / 64;   // x is [N,64]
    const int E = in_sizes[1] / 2;    // edge_index is [2,E]

    // ws: xl[N*64]f32 + xr[N*64]f32 + deg[N]i32 + slot[N*CAP]i32 = 77.2 MB
    float* w = (float*)d_ws;
    float* xl  = w;                   w += (size_t)N * 64;
    float* xr  = w;                   w += (size_t)N * 64;
    int* deg   = (int*)w;
    int* slot  = deg + N;

    float* out = (float*)d_out;

    // 2048 blocks: 1024/side, even split; also covers deg-zeroing of N
    k_node_linear<<<2048, 256, 0, stream>>>(
        x, Wl, bl, Wr, br, xl, xr, deg, N);

    k_bucket<<<(E + 255) / 256, 256, 0, stream>>>(ei, deg, slot, E);

    k_gather<<<(N + 3) / 4, 256, 0, stream>>>(
        ei, ea, We, att, xl, xr, deg, slot, x, bias, gamma, beta, out, N);
}